// Round 11
// baseline (142.780 us; speedup 1.0000x reference)
//
#include <hip/hip_runtime.h>

#define PI_F 3.14159265358979323846f

typedef _Float16 half2v __attribute__((ext_vector_type(2)));
typedef _Float16 half4v __attribute__((ext_vector_type(4)));
typedef _Float16 half8v __attribute__((ext_vector_type(8)));
typedef float f32x4 __attribute__((ext_vector_type(4)));

struct C2 { float x, y; };
__device__ __forceinline__ C2 cmul(C2 a, C2 b) {
    return C2{a.x * b.x - a.y * b.y, a.x * b.y + a.y * b.x};
}

__device__ __forceinline__ void gate1(float& re, float& im, int l, int w,
                                      C2 m00, C2 m01, C2 m10, C2 m11) {
    int mask = 1 << (3 - w);
    float pre = __shfl_xor(re, mask, 64);
    float pim = __shfl_xor(im, mask, 64);
    bool b = (l & mask) != 0;
    C2 d = b ? m11 : m00;
    C2 o = b ? m10 : m01;
    float nre = d.x * re - d.y * im + o.x * pre - o.y * pim;
    float nim = d.x * im + d.y * re + o.x * pim + o.y * pre;
    re = nre; im = nim;
}

// p1f: [ic-half sel (2)][pixel (16 rows x 17 cols)][8 halves]
// bank of a pixel's 16B entry = 4*(pix%8) -> worst ~2-way across a kq-group.
#define P1_PIX 272                    // 16*17
#define P1_SEL (P1_PIX * 8)           // 2176 halves per sel

// ws layout (floats):
//   [0..2559]    conv2 B-frags (half8 per lane per (kstep,ntile))
//   [2560..2687] conv1 B-frags (half4 per lane)
//   [2688..8959] dwT: dense_w transposed, float4 per (oc*49+pixel)
//   [8960..9023] rot gates; [9024..9047] ent gates
#define WS_C1B 2560
#define WS_DWT 2688
#define WS_GROT 8960
#define WS_GENT 9024

// ---------------- prologue: batch-invariant precompute ----------------
__global__ __launch_bounds__(256) void qnn_prep(
    const float* __restrict__ w1g, const float* __restrict__ w2g,
    const float* __restrict__ dwg, const float* __restrict__ qpg,
    float* __restrict__ ws)
{
    int t = threadIdx.x;
    for (int e = t; e < 640; e += 256) {          // conv2 B-fragments
        int kstep = e >> 7, rem = e & 127;
        int ntile = rem >> 6, lane = rem & 63;
        int kq = lane >> 4, n = lane & 15;
        int oc = ntile * 16 + n;
        int pi = kstep * 2 + (kq >> 1);
        half8v h;
        #pragma unroll
        for (int jj = 0; jj < 8; ++jj) {
            int ic = (kq & 1) * 8 + jj;
            float v = (pi < 9) ? w2g[oc * 144 + ic * 9 + pi] : 0.f;
            h[jj] = (_Float16)v;
        }
        *(float4*)(ws + e * 4) = __builtin_bit_cast(float4, h);
    }
    if (t < 64) {                                 // conv1 B-fragments
        int ky = t >> 4, n = t & 15;
        half4v h;
        #pragma unroll
        for (int j = 0; j < 4; ++j) {
            float v = (ky < 3 && j < 3) ? w1g[n * 9 + ky * 3 + j] : 0.f;
            h[j] = (_Float16)v;
        }
        *(float2*)(ws + WS_C1B + t * 2) = __builtin_bit_cast(float2, h);
    }
    for (int e = t; e < 1568; e += 256) {         // dense_w transpose
        float4 v = {dwg[e], dwg[1568 + e], dwg[3136 + e], dwg[4704 + e]};
        *(float4*)(ws + WS_DWT + e * 4) = v;
    }
    if (t < 8) {                                  // rot gates
        int layer = t >> 2, q = t & 3;
        int st = layer * 18;
        float a0 = qpg[st + 3 * q], a1 = qpg[st + 3 * q + 1], a2 = qpg[st + 3 * q + 2];
        float cx = cosf(0.5f * a0), sx = sinf(0.5f * a0);
        float cy = cosf(0.5f * a1), sy = sinf(0.5f * a1);
        float cz = cosf(0.5f * a2), sz = sinf(0.5f * a2);
        C2 T00{cy * cx,  sy * sx}, T01{-sy * cx, -cy * sx};
        C2 T10{sy * cx, -cy * sx}, T11{ cy * cx, -sy * sx};
        C2 E0{cz, -sz}, E1{cz, sz};
        C2 m00 = cmul(E0, T00), m01 = cmul(E0, T01);
        C2 m10 = cmul(E1, T10), m11 = cmul(E1, T11);
        float* gm = ws + WS_GROT + t * 8;
        gm[0] = m00.x; gm[1] = m00.y; gm[2] = m01.x; gm[3] = m01.y;
        gm[4] = m10.x; gm[5] = m10.y; gm[6] = m11.x; gm[7] = m11.y;
    }
    if (t >= 32 && t < 44) {                      // entangler RZ phases
        int k = t - 32;
        float e = qpg[(k / 6) * 18 + 12 + (k % 6)];
        ws[WS_GENT + k * 2]     = cosf(0.5f * e);
        ws[WS_GENT + k * 2 + 1] = sinf(0.5f * e);
    }
}

__global__ __launch_bounds__(256, 8) void qnn_fused(
    const float* __restrict__ xg,
    const float* __restrict__ b1g, const float* __restrict__ b2g,
    const float* __restrict__ dbg,
    const float* __restrict__ wsc,
    const float* __restrict__ pwg, const float* __restrict__ pbg,
    float* __restrict__ out)
{
    const int b = blockIdx.x;
    const int t = threadIdx.x;
    const int lane = t & 63;
    const int wv = __builtin_amdgcn_readfirstlane(t >> 6);
    const int kq = lane >> 4;
    const int lm = lane & 15;

    // xp[i] = half2{h[i], h[i+1]} of the padded 30x30 raster (overlapping
    // pairs) -> phase-1 A-frag = two aligned b32 reads, zero repack.
    __shared__ __align__(16) unsigned xp[932];
    __shared__ __align__(16) _Float16 p1f[2 * P1_SEL];    // 8704 B
    __shared__ __align__(16) float angp[16];

    // ---- preload B-fragments (L2-hot; latency hidden by phase 0)
    half8v bC2[5][2];
    {
        const float4* wsB = (const float4*)wsc;
        #pragma unroll
        for (int ks = 0; ks < 5; ++ks)
            #pragma unroll
            for (int nt = 0; nt < 2; ++nt)
                bC2[ks][nt] = __builtin_bit_cast(half8v, wsB[(ks * 2 + nt) * 64 + lane]);
    }
    half4v bC1 = __builtin_bit_cast(half4v, *(const float2*)(wsc + WS_C1B + lane * 2));
    float bias1 = b1g[lm];
    float b20 = b2g[lm], b21 = b2g[16 + lm];

    // ---------------- phase 0: stage x as overlapping f16 pairs -------------
    const float* xb = xg + (size_t)b * 784;
    {
        int y = t / 30, x = t - y * 30;           // div once, then increment
        for (int i = t; i < 930; i += 256) {
            bool in1 = (y >= 1 && y <= 28 && x >= 1 && x <= 28);
            float v1 = in1 ? xb[(y - 1) * 28 + (x - 1)] : 0.f;
            int y2 = y, x2 = x + 1;
            if (x2 == 30) { x2 = 0; y2 = y + 1; }
            bool in2 = (y2 >= 1 && y2 <= 28 && x2 >= 1 && x2 <= 28);
            float v2 = in2 ? xb[(y2 - 1) * 28 + (x2 - 1)] : 0.f;
            half2v p;
            p.x = (_Float16)v1;
            p.y = (_Float16)v2;
            xp[i] = __builtin_bit_cast(unsigned, p);
            x += 16; y += 8; if (x >= 30) { x -= 30; y += 1; }
        }
        if (t < 2) xp[930 + t] = 0u;
    }
    {   // zero p1f: 544 uint4
        uint4 z4 = {0u, 0u, 0u, 0u};
        uint4* p4 = (uint4*)p1f;
        #pragma unroll
        for (int j = 0; j < 3; ++j) {
            int i = t + j * 256;
            if (i < 544) p4[i] = z4;
        }
    }
    __syncthreads();

    // ---------------- phase 1: conv1 via MFMA 16x16x16 (pure f16) -----------
    // A-frag: 4 contiguous raster halves = uint2{xp[base], xp[base+2]}.
    {
        int kyc = (kq < 3) ? kq : 0;              // kq==3 rows have zero weights
        int pos = lm & 3;
        int pyo = pos >> 1, pxo = pos & 1;
        int p14 = wv * 4 + (lm >> 2);
        int Y = p14 / 14, X = p14 - Y * 14;
        int q14 = wv * 4 + kq;
        int r = q14 / 14, c = q14 - r * 14;
        for (int tile = wv; tile < 49; tile += 4) {
            int py = 2 * Y + pyo, px = 2 * X + pxo;
            int base = (py + kyc) * 30 + px;
            uint2 u = {xp[base], xp[base + 2]};
            half4v a = __builtin_bit_cast(half4v, u);
            f32x4 acc = {bias1, bias1, bias1, bias1};
            acc = __builtin_amdgcn_mfma_f32_16x16x16f16(a, bC1, acc, 0, 0, 0);
            float v = fmaxf(fmaxf(acc.x, acc.y), fmaxf(acc.z, acc.w));
            v = fmaxf(v, 0.f);
            int pixw = (r + 1) * 17 + (c + 1);
            p1f[(lm >> 3) * P1_SEL + pixw * 8 + (lm & 7)] = (_Float16)v;
            X += 2; Y += 1; if (X >= 14) { X -= 14; Y += 1; }
            c += 2; r += 1; if (c >= 14) { c -= 14; r += 1; }
        }
    }
    __syncthreads();

    // ---------------- phase 2: conv2 via MFMA 16x16x32 + fused dense --------
    {
        float dp0 = 0.f, dp1 = 0.f, dp2 = 0.f, dp3 = 0.f;
        const float4* dt = (const float4*)(wsc + WS_DWT);
        const _Float16* pfs = p1f + (kq & 1) * P1_SEL;  // lane's ic-half bank
        for (int tile = wv; tile < 13; tile += 4) {
            int m = tile * 16 + lm;
            int quad = m >> 2; if (quad > 48) quad = 48;
            int pos = m & 3;
            int Y = quad / 7, X = quad - Y * 7;
            int py = 2 * Y + (pos >> 1), px = 2 * X + (pos & 1);
            int pixb = py * 17 + px;
            f32x4 acc0 = {b20, b20, b20, b20};
            f32x4 acc1 = {b21, b21, b21, b21};
            #pragma unroll
            for (int ks = 0; ks < 5; ++ks) {
                int pi = ks * 2 + (kq >> 1);
                if (pi > 8) pi = 8;               // pad k -> zero B
                int ky = (pi >= 6) ? 2 : ((pi >= 3) ? 1 : 0);
                int kx = pi - ky * 3;
                half8v a = *(const half8v*)(&pfs[(pixb + ky * 17 + kx) * 8]);
                acc0 = __builtin_amdgcn_mfma_f32_16x16x32_f16(a, bC2[ks][0], acc0, 0, 0, 0);
                acc1 = __builtin_amdgcn_mfma_f32_16x16x32_f16(a, bC2[ks][1], acc1, 0, 0, 0);
            }
            int quadO = tile * 4 + kq;
            if (quadO < 49) {
                float v0 = fmaxf(fmaxf(fmaxf(acc0.x, acc0.y), fmaxf(acc0.z, acc0.w)), 0.f);
                float v1 = fmaxf(fmaxf(fmaxf(acc1.x, acc1.y), fmaxf(acc1.z, acc1.w)), 0.f);
                float4 q0 = dt[lm * 49 + quadO];
                float4 q1 = dt[(16 + lm) * 49 + quadO];
                dp0 = fmaf(v0, q0.x, fmaf(v1, q1.x, dp0));
                dp1 = fmaf(v0, q0.y, fmaf(v1, q1.y, dp1));
                dp2 = fmaf(v0, q0.z, fmaf(v1, q1.z, dp2));
                dp3 = fmaf(v0, q0.w, fmaf(v1, q1.w, dp3));
            }
        }
        #pragma unroll
        for (int m = 32; m >= 1; m >>= 1) {
            dp0 += __shfl_xor(dp0, m, 64);
            dp1 += __shfl_xor(dp1, m, 64);
            dp2 += __shfl_xor(dp2, m, 64);
            dp3 += __shfl_xor(dp3, m, 64);
        }
        if (lane == 0) {
            float4 dpv = {dp0, dp1, dp2, dp3};
            *(float4*)&angp[wv * 4] = dpv;
        }
    }
    __syncthreads();

    // ---------------- phase 3: quantum sim + post linear (wave 0 only) ------
    if (t < 64) {
        float4 a0v = *(const float4*)&angp[0];
        float4 a1v = *(const float4*)&angp[4];
        float4 a2v = *(const float4*)&angp[8];
        float4 a3v = *(const float4*)&angp[12];
        float aw[4] = {a0v.x + a1v.x + a2v.x + a3v.x + dbg[0],
                       a0v.y + a1v.y + a2v.y + a3v.y + dbg[1],
                       a0v.z + a1v.z + a2v.z + a3v.z + dbg[2],
                       a0v.w + a1v.w + a2v.w + a3v.w + dbg[3]};
        int l = t & 15;
        float re = (l == 0) ? 1.f : 0.f;
        float im = 0.f;
        #pragma unroll
        for (int w = 0; w < 4; ++w) {      // initial RY(angle * pi)
            float th = aw[w] * (PI_F * 0.5f);
            float c = cosf(th), s = sinf(th);
            gate1(re, im, l, w, C2{c, 0.f}, C2{-s, 0.f}, C2{s, 0.f}, C2{c, 0.f});
        }
        #pragma unroll
        for (int layer = 0; layer < 2; ++layer) {
            #pragma unroll
            for (int q = 0; q < 4; ++q) {
                const float* gm = wsc + WS_GROT + (layer * 4 + q) * 8;
                gate1(re, im, l, q, C2{gm[0], gm[1]}, C2{gm[2], gm[3]},
                                     C2{gm[4], gm[5]}, C2{gm[6], gm[7]});
            }
            const int pi_[6] = {0, 0, 0, 1, 1, 2};
            const int pj_[6] = {1, 2, 3, 2, 3, 3};
            #pragma unroll
            for (int k = 0; k < 6; ++k) {
                int i = pi_[k], j = pj_[k];
                const float* em = wsc + WS_GENT + (layer * 6 + k) * 2;
                float ce = em[0], se = em[1];
                int maskj = 1 << (3 - j);
                float pre = __shfl_xor(re, maskj, 64);
                float pim = __shfl_xor(im, maskj, 64);
                bool bi = ((l >> (3 - i)) & 1) != 0;
                re = bi ? pre : re;
                im = bi ? pim : im;
                bool bj = (l & maskj) != 0;
                C2 ph{ce, bj ? se : -se};
                C2 r = cmul(C2{re, im}, ph);
                re = r.x; im = r.y;
            }
        }
        float pr = re * re + im * im;
        float z0 = ((l >> 3) & 1) ? -pr : pr;
        float z1 = ((l >> 2) & 1) ? -pr : pr;
        float z2 = ((l >> 1) & 1) ? -pr : pr;
        float z3 = (l & 1)        ? -pr : pr;
        #pragma unroll
        for (int m = 1; m <= 8; m <<= 1) {
            z0 += __shfl_xor(z0, m, 64);
            z1 += __shfl_xor(z1, m, 64);
            z2 += __shfl_xor(z2, m, 64);
            z3 += __shfl_xor(z3, m, 64);
        }
        if (t < 10) {
            float4 pw4 = *(const float4*)(pwg + t * 4);
            float o = pbg[t];
            o = fmaf(z0, pw4.x, o); o = fmaf(z1, pw4.y, o);
            o = fmaf(z2, pw4.z, o); o = fmaf(z3, pw4.w, o);
            out[(size_t)b * 10 + t] = o;
        }
    }
}

extern "C" void kernel_launch(void* const* d_in, const int* in_sizes, int n_in,
                              void* d_out, int out_size, void* d_ws, size_t ws_size,
                              hipStream_t stream) {
    const float* x  = (const float*)d_in[0];
    const float* w1 = (const float*)d_in[1];
    const float* b1 = (const float*)d_in[2];
    const float* w2 = (const float*)d_in[3];
    const float* b2 = (const float*)d_in[4];
    const float* dw = (const float*)d_in[5];
    const float* db = (const float*)d_in[6];
    const float* qp = (const float*)d_in[7];
    const float* pw = (const float*)d_in[8];
    const float* pb = (const float*)d_in[9];
    float* out = (float*)d_out;
    float* ws  = (float*)d_ws;
    int B = in_sizes[0] / 784;   // 4096

    qnn_prep<<<1, 256, 0, stream>>>(w1, w2, dw, qp, ws);
    qnn_fused<<<B, 256, 0, stream>>>(x, b1, b2, db, ws, pw, pb, out);
}

// Round 12
// 117.862 us; speedup vs baseline: 1.2114x; 1.2114x over previous
//
#include <hip/hip_runtime.h>

#define PI_F 3.14159265358979323846f

typedef _Float16 half2v __attribute__((ext_vector_type(2)));
typedef _Float16 half4v __attribute__((ext_vector_type(4)));
typedef _Float16 half8v __attribute__((ext_vector_type(8)));
typedef float f32x4 __attribute__((ext_vector_type(4)));

struct C2 { float x, y; };
__device__ __forceinline__ C2 cmul(C2 a, C2 b) {
    return C2{a.x * b.x - a.y * b.y, a.x * b.y + a.y * b.x};
}

__device__ __forceinline__ void gate1(float& re, float& im, int l, int w,
                                      C2 m00, C2 m01, C2 m10, C2 m11) {
    int mask = 1 << (3 - w);
    float pre = __shfl_xor(re, mask, 64);
    float pim = __shfl_xor(im, mask, 64);
    bool b = (l & mask) != 0;
    C2 d = b ? m11 : m00;
    C2 o = b ? m10 : m01;
    float nre = d.x * re - d.y * im + o.x * pre - o.y * pim;
    float nim = d.x * im + d.y * re + o.x * pim + o.y * pre;
    re = nre; im = nim;
}

// p1f: [ic-half sel (2)][pixel (16 rows x 17 cols)][8 halves]
// bank of a pixel's 16B entry = 4*(pix%8) -> worst ~2-way across a kq-group.
#define P1_PIX 272                    // 16*17
#define P1_SEL (P1_PIX * 8)           // 2176 halves per sel

// ws layout (floats):
//   [0..2559]    conv2 B-frags (half8 per lane per (kstep,ntile))
//   [2560..2687] conv1 B-frags (half4 per lane)
//   [2688..8959] dwT: dense_w transposed, float4 per (oc*49+pixel)
//   [8960..9023] rot gates; [9024..9047] ent gates
#define WS_C1B 2560
#define WS_DWT 2688
#define WS_GROT 8960
#define WS_GENT 9024

// ---------------- prologue: batch-invariant precompute ----------------
__global__ __launch_bounds__(256) void qnn_prep(
    const float* __restrict__ w1g, const float* __restrict__ w2g,
    const float* __restrict__ dwg, const float* __restrict__ qpg,
    float* __restrict__ ws)
{
    int t = threadIdx.x;
    for (int e = t; e < 640; e += 256) {          // conv2 B-fragments
        int kstep = e >> 7, rem = e & 127;
        int ntile = rem >> 6, lane = rem & 63;
        int kq = lane >> 4, n = lane & 15;
        int oc = ntile * 16 + n;
        int pi = kstep * 2 + (kq >> 1);
        half8v h;
        #pragma unroll
        for (int jj = 0; jj < 8; ++jj) {
            int ic = (kq & 1) * 8 + jj;
            float v = (pi < 9) ? w2g[oc * 144 + ic * 9 + pi] : 0.f;
            h[jj] = (_Float16)v;
        }
        *(float4*)(ws + e * 4) = __builtin_bit_cast(float4, h);
    }
    if (t < 64) {                                 // conv1 B-fragments
        int ky = t >> 4, n = t & 15;
        half4v h;
        #pragma unroll
        for (int j = 0; j < 4; ++j) {
            float v = (ky < 3 && j < 3) ? w1g[n * 9 + ky * 3 + j] : 0.f;
            h[j] = (_Float16)v;
        }
        *(float2*)(ws + WS_C1B + t * 2) = __builtin_bit_cast(float2, h);
    }
    for (int e = t; e < 1568; e += 256) {         // dense_w transpose
        float4 v = {dwg[e], dwg[1568 + e], dwg[3136 + e], dwg[4704 + e]};
        *(float4*)(ws + WS_DWT + e * 4) = v;
    }
    if (t < 8) {                                  // rot gates
        int layer = t >> 2, q = t & 3;
        int st = layer * 18;
        float a0 = qpg[st + 3 * q], a1 = qpg[st + 3 * q + 1], a2 = qpg[st + 3 * q + 2];
        float cx = cosf(0.5f * a0), sx = sinf(0.5f * a0);
        float cy = cosf(0.5f * a1), sy = sinf(0.5f * a1);
        float cz = cosf(0.5f * a2), sz = sinf(0.5f * a2);
        C2 T00{cy * cx,  sy * sx}, T01{-sy * cx, -cy * sx};
        C2 T10{sy * cx, -cy * sx}, T11{ cy * cx, -sy * sx};
        C2 E0{cz, -sz}, E1{cz, sz};
        C2 m00 = cmul(E0, T00), m01 = cmul(E0, T01);
        C2 m10 = cmul(E1, T10), m11 = cmul(E1, T11);
        float* gm = ws + WS_GROT + t * 8;
        gm[0] = m00.x; gm[1] = m00.y; gm[2] = m01.x; gm[3] = m01.y;
        gm[4] = m10.x; gm[5] = m10.y; gm[6] = m11.x; gm[7] = m11.y;
    }
    if (t >= 32 && t < 44) {                      // entangler RZ phases
        int k = t - 32;
        float e = qpg[(k / 6) * 18 + 12 + (k % 6)];
        ws[WS_GENT + k * 2]     = cosf(0.5f * e);
        ws[WS_GENT + k * 2 + 1] = sinf(0.5f * e);
    }
}

__global__ __launch_bounds__(256, 6) void qnn_fused(
    const float* __restrict__ xg,
    const float* __restrict__ b1g, const float* __restrict__ b2g,
    const float* __restrict__ dbg,
    const float* __restrict__ wsc,
    const float* __restrict__ pwg, const float* __restrict__ pbg,
    float* __restrict__ out)
{
    const int b = blockIdx.x;
    const int t = threadIdx.x;
    const int lane = t & 63;
    const int wv = __builtin_amdgcn_readfirstlane(t >> 6);
    const int kq = lane >> 4;
    const int lm = lane & 15;

    // xp[i] = half2{h[i], h[i+1]} of the padded 30x30 raster (overlapping
    // pairs) -> phase-1 A-frag = two aligned b32 reads, zero repack.
    __shared__ __align__(16) unsigned xp[932];
    __shared__ __align__(16) _Float16 p1f[2 * P1_SEL];    // 8704 B
    __shared__ __align__(16) float angp[16];

    // ---- preload B-fragments (L2-hot; latency hidden by phase 0)
    half8v bC2[5][2];
    {
        const float4* wsB = (const float4*)wsc;
        #pragma unroll
        for (int ks = 0; ks < 5; ++ks)
            #pragma unroll
            for (int nt = 0; nt < 2; ++nt)
                bC2[ks][nt] = __builtin_bit_cast(half8v, wsB[(ks * 2 + nt) * 64 + lane]);
    }
    half4v bC1 = __builtin_bit_cast(half4v, *(const float2*)(wsc + WS_C1B + lane * 2));
    float bias1 = b1g[lm];
    float b20 = b2g[lm], b21 = b2g[16 + lm];

    // ---------------- phase 0: stage x as overlapping f16 pairs -------------
    const float* xb = xg + (size_t)b * 784;
    {
        int y = t / 30, x = t - y * 30;           // div once, then increment
        for (int i = t; i < 930; i += 256) {
            bool in1 = (y >= 1 && y <= 28 && x >= 1 && x <= 28);
            float v1 = in1 ? xb[(y - 1) * 28 + (x - 1)] : 0.f;
            int y2 = y, x2 = x + 1;
            if (x2 == 30) { x2 = 0; y2 = y + 1; }
            bool in2 = (y2 >= 1 && y2 <= 28 && x2 >= 1 && x2 <= 28);
            float v2 = in2 ? xb[(y2 - 1) * 28 + (x2 - 1)] : 0.f;
            half2v p;
            p.x = (_Float16)v1;
            p.y = (_Float16)v2;
            xp[i] = __builtin_bit_cast(unsigned, p);
            x += 16; y += 8; if (x >= 30) { x -= 30; y += 1; }
        }
        if (t < 2) xp[930 + t] = 0u;
    }
    {   // zero p1f: 544 uint4
        uint4 z4 = {0u, 0u, 0u, 0u};
        uint4* p4 = (uint4*)p1f;
        #pragma unroll
        for (int j = 0; j < 3; ++j) {
            int i = t + j * 256;
            if (i < 544) p4[i] = z4;
        }
    }
    __syncthreads();

    // ---------------- phase 1: conv1 via MFMA 16x16x16 (pure f16) -----------
    // A-frag: 4 contiguous raster halves = uint2{xp[base], xp[base+2]}.
    {
        int kyc = (kq < 3) ? kq : 0;              // kq==3 rows have zero weights
        int pos = lm & 3;
        int pyo = pos >> 1, pxo = pos & 1;
        int p14 = wv * 4 + (lm >> 2);
        int Y = p14 / 14, X = p14 - Y * 14;
        int q14 = wv * 4 + kq;
        int r = q14 / 14, c = q14 - r * 14;
        for (int tile = wv; tile < 49; tile += 4) {
            int py = 2 * Y + pyo, px = 2 * X + pxo;
            int base = (py + kyc) * 30 + px;
            uint2 u = {xp[base], xp[base + 2]};
            half4v a = __builtin_bit_cast(half4v, u);
            f32x4 acc = {bias1, bias1, bias1, bias1};
            acc = __builtin_amdgcn_mfma_f32_16x16x16f16(a, bC1, acc, 0, 0, 0);
            float v = fmaxf(fmaxf(acc.x, acc.y), fmaxf(acc.z, acc.w));
            v = fmaxf(v, 0.f);
            int pixw = (r + 1) * 17 + (c + 1);
            p1f[(lm >> 3) * P1_SEL + pixw * 8 + (lm & 7)] = (_Float16)v;
            X += 2; Y += 1; if (X >= 14) { X -= 14; Y += 1; }
            c += 2; r += 1; if (c >= 14) { c -= 14; r += 1; }
        }
    }
    __syncthreads();

    // ---------------- phase 2: conv2 via MFMA 16x16x32 + fused dense --------
    {
        float dp0 = 0.f, dp1 = 0.f, dp2 = 0.f, dp3 = 0.f;
        const float4* dt = (const float4*)(wsc + WS_DWT);
        const _Float16* pfs = p1f + (kq & 1) * P1_SEL;  // lane's ic-half bank
        for (int tile = wv; tile < 13; tile += 4) {
            int m = tile * 16 + lm;
            int quad = m >> 2; if (quad > 48) quad = 48;
            int pos = m & 3;
            int Y = quad / 7, X = quad - Y * 7;
            int py = 2 * Y + (pos >> 1), px = 2 * X + (pos & 1);
            int pixb = py * 17 + px;
            f32x4 acc0 = {b20, b20, b20, b20};
            f32x4 acc1 = {b21, b21, b21, b21};
            #pragma unroll
            for (int ks = 0; ks < 5; ++ks) {
                int pi = ks * 2 + (kq >> 1);
                if (pi > 8) pi = 8;               // pad k -> zero B
                int ky = (pi >= 6) ? 2 : ((pi >= 3) ? 1 : 0);
                int kx = pi - ky * 3;
                half8v a = *(const half8v*)(&pfs[(pixb + ky * 17 + kx) * 8]);
                acc0 = __builtin_amdgcn_mfma_f32_16x16x32_f16(a, bC2[ks][0], acc0, 0, 0, 0);
                acc1 = __builtin_amdgcn_mfma_f32_16x16x32_f16(a, bC2[ks][1], acc1, 0, 0, 0);
            }
            int quadO = tile * 4 + kq;
            if (quadO < 49) {
                float v0 = fmaxf(fmaxf(fmaxf(acc0.x, acc0.y), fmaxf(acc0.z, acc0.w)), 0.f);
                float v1 = fmaxf(fmaxf(fmaxf(acc1.x, acc1.y), fmaxf(acc1.z, acc1.w)), 0.f);
                float4 q0 = dt[lm * 49 + quadO];
                float4 q1 = dt[(16 + lm) * 49 + quadO];
                dp0 = fmaf(v0, q0.x, fmaf(v1, q1.x, dp0));
                dp1 = fmaf(v0, q0.y, fmaf(v1, q1.y, dp1));
                dp2 = fmaf(v0, q0.z, fmaf(v1, q1.z, dp2));
                dp3 = fmaf(v0, q0.w, fmaf(v1, q1.w, dp3));
            }
        }
        #pragma unroll
        for (int m = 32; m >= 1; m >>= 1) {
            dp0 += __shfl_xor(dp0, m, 64);
            dp1 += __shfl_xor(dp1, m, 64);
            dp2 += __shfl_xor(dp2, m, 64);
            dp3 += __shfl_xor(dp3, m, 64);
        }
        if (lane == 0) {
            float4 dpv = {dp0, dp1, dp2, dp3};
            *(float4*)&angp[wv * 4] = dpv;
        }
    }
    __syncthreads();

    // ---------------- phase 3: quantum sim + post linear (wave 0 only) ------
    if (t < 64) {
        float4 a0v = *(const float4*)&angp[0];
        float4 a1v = *(const float4*)&angp[4];
        float4 a2v = *(const float4*)&angp[8];
        float4 a3v = *(const float4*)&angp[12];
        float aw[4] = {a0v.x + a1v.x + a2v.x + a3v.x + dbg[0],
                       a0v.y + a1v.y + a2v.y + a3v.y + dbg[1],
                       a0v.z + a1v.z + a2v.z + a3v.z + dbg[2],
                       a0v.w + a1v.w + a2v.w + a3v.w + dbg[3]};
        int l = t & 15;
        float re = (l == 0) ? 1.f : 0.f;
        float im = 0.f;
        #pragma unroll
        for (int w = 0; w < 4; ++w) {      // initial RY(angle * pi)
            float th = aw[w] * (PI_F * 0.5f);
            float c = cosf(th), s = sinf(th);
            gate1(re, im, l, w, C2{c, 0.f}, C2{-s, 0.f}, C2{s, 0.f}, C2{c, 0.f});
        }
        #pragma unroll
        for (int layer = 0; layer < 2; ++layer) {
            #pragma unroll
            for (int q = 0; q < 4; ++q) {
                const float* gm = wsc + WS_GROT + (layer * 4 + q) * 8;
                gate1(re, im, l, q, C2{gm[0], gm[1]}, C2{gm[2], gm[3]},
                                     C2{gm[4], gm[5]}, C2{gm[6], gm[7]});
            }
            const int pi_[6] = {0, 0, 0, 1, 1, 2};
            const int pj_[6] = {1, 2, 3, 2, 3, 3};
            #pragma unroll
            for (int k = 0; k < 6; ++k) {
                int i = pi_[k], j = pj_[k];
                const float* em = wsc + WS_GENT + (layer * 6 + k) * 2;
                float ce = em[0], se = em[1];
                int maskj = 1 << (3 - j);
                float pre = __shfl_xor(re, maskj, 64);
                float pim = __shfl_xor(im, maskj, 64);
                bool bi = ((l >> (3 - i)) & 1) != 0;
                re = bi ? pre : re;
                im = bi ? pim : im;
                bool bj = (l & maskj) != 0;
                C2 ph{ce, bj ? se : -se};
                C2 r = cmul(C2{re, im}, ph);
                re = r.x; im = r.y;
            }
        }
        float pr = re * re + im * im;
        float z0 = ((l >> 3) & 1) ? -pr : pr;
        float z1 = ((l >> 2) & 1) ? -pr : pr;
        float z2 = ((l >> 1) & 1) ? -pr : pr;
        float z3 = (l & 1)        ? -pr : pr;
        #pragma unroll
        for (int m = 1; m <= 8; m <<= 1) {
            z0 += __shfl_xor(z0, m, 64);
            z1 += __shfl_xor(z1, m, 64);
            z2 += __shfl_xor(z2, m, 64);
            z3 += __shfl_xor(z3, m, 64);
        }
        if (t < 10) {
            float4 pw4 = *(const float4*)(pwg + t * 4);
            float o = pbg[t];
            o = fmaf(z0, pw4.x, o); o = fmaf(z1, pw4.y, o);
            o = fmaf(z2, pw4.z, o); o = fmaf(z3, pw4.w, o);
            out[(size_t)b * 10 + t] = o;
        }
    }
}

extern "C" void kernel_launch(void* const* d_in, const int* in_sizes, int n_in,
                              void* d_out, int out_size, void* d_ws, size_t ws_size,
                              hipStream_t stream) {
    const float* x  = (const float*)d_in[0];
    const float* w1 = (const float*)d_in[1];
    const float* b1 = (const float*)d_in[2];
    const float* w2 = (const float*)d_in[3];
    const float* b2 = (const float*)d_in[4];
    const float* dw = (const float*)d_in[5];
    const float* db = (const float*)d_in[6];
    const float* qp = (const float*)d_in[7];
    const float* pw = (const float*)d_in[8];
    const float* pb = (const float*)d_in[9];
    float* out = (float*)d_out;
    float* ws  = (float*)d_ws;
    int B = in_sizes[0] / 784;   // 4096

    qnn_prep<<<1, 256, 0, stream>>>(w1, w2, dw, qp, ws);
    qnn_fused<<<B, 256, 0, stream>>>(x, b1, b2, db, ws, pw, pb, out);
}